// Round 1
// baseline (1018.072 us; speedup 1.0000x reference)
//
#include <hip/hip_runtime.h>

#define NN 50000
#define NE 640000
#define DD 128

typedef float f32x4 __attribute__((ext_vector_type(4)));
typedef __bf16 bf16x8 __attribute__((ext_vector_type(8)));
typedef unsigned short u16x8 __attribute__((ext_vector_type(8)));

__device__ inline __bf16 f2bf(float f) {
  unsigned u = __builtin_bit_cast(unsigned, f);
  u = (u + 0x7fffu + ((u >> 16) & 1u)) >> 16;
  unsigned short h = (unsigned short)u;
  return __builtin_bit_cast(__bf16, h);
}

__device__ inline bf16x8 load8(const float* __restrict__ p) {
  f32x4 a = *(const f32x4*)p;
  f32x4 b = *(const f32x4*)(p + 4);
  bf16x8 o;
  o[0] = f2bf(a[0]); o[1] = f2bf(a[1]); o[2] = f2bf(a[2]); o[3] = f2bf(a[3]);
  o[4] = f2bf(b[0]); o[5] = f2bf(b[1]); o[6] = f2bf(b[2]); o[7] = f2bf(b[3]);
  return o;
}

#define MFMA16(a, b, c) __builtin_amdgcn_mfma_f32_16x16x32_bf16((a), (b), (c), 0, 0, 0)

// ---- prep: transpose + convert the 4 weight matrices to bf16 Bt[n][k] ----
__global__ void prep_kernel(const float* __restrict__ We1, const float* __restrict__ We2,
                            const float* __restrict__ Wn1, const float* __restrict__ Wn2,
                            __bf16* __restrict__ We1t, __bf16* __restrict__ We2t,
                            __bf16* __restrict__ Wn1t, __bf16* __restrict__ Wn2t) {
  int i = blockIdx.x * blockDim.x + threadIdx.x;
  if (i < 49152) {                       // We1: [384][128] -> [128][384]
    int n = i / 384, k = i % 384;
    We1t[i] = f2bf(We1[k * 128 + n]);
  } else if (i < 65536) {                // We2: [128][128]
    int j = i - 49152; int n = j / 128, k = j % 128;
    We2t[j] = f2bf(We2[k * 128 + n]);
  } else if (i < 98304) {                // Wn1: [256][128] -> [128][256]
    int j = i - 65536; int n = j / 256, k = j % 256;
    Wn1t[j] = f2bf(Wn1[k * 128 + n]);
  } else if (i < 114688) {               // Wn2: [128][128]
    int j = i - 98304; int n = j / 128, k = j % 128;
    Wn2t[j] = f2bf(Wn2[k * 128 + n]);
  }
}

// ---- edge MLP + scatter-add: tile = 128 edges x 128 out, 4 waves ----
__global__ __launch_bounds__(256) void edge_kernel(
    const float* __restrict__ node_h, const float* __restrict__ edge_h,
    const int* __restrict__ src, const int* __restrict__ dst,
    const __bf16* __restrict__ We1t, const float* __restrict__ be1,
    const __bf16* __restrict__ We2t, const float* __restrict__ be2,
    float* __restrict__ agg) {
  __shared__ unsigned short h1[128 * 136];   // +8 pad: 2-way (free) LDS access
  const int tid = (int)threadIdx.x;
  const int w = tid >> 6;
  const int l = tid & 63;
  const int lm = l & 15;
  const int q = l >> 4;
  const int e0 = (int)blockIdx.x * 128;
  const int row0 = w * 32;

  const int eA0 = e0 + row0 + lm;
  const int eA1 = eA0 + 16;
  const float* srcA0[3];
  const float* srcA1[3];
  srcA0[0] = node_h + (size_t)src[eA0] * DD;
  srcA0[1] = node_h + (size_t)dst[eA0] * DD;
  srcA0[2] = edge_h + (size_t)eA0 * DD;
  srcA1[0] = node_h + (size_t)src[eA1] * DD;
  srcA1[1] = node_h + (size_t)dst[eA1] * DD;
  srcA1[2] = edge_h + (size_t)eA1 * DD;

  f32x4 acc[2][8];
#pragma unroll
  for (int nt = 0; nt < 8; ++nt) {
    float b = be1[nt * 16 + lm];
    acc[0][nt] = (f32x4){b, b, b, b};
    acc[1][nt] = (f32x4){b, b, b, b};
  }

  // phase 1: relu(e_in @ We1 + be1), K = 384
#pragma unroll
  for (int step = 0; step < 12; ++step) {
    const int region = step >> 2;                  // 0:src-h 1:dst-h 2:edge-h
    const int col = ((step & 3) * 32) + q * 8;
    bf16x8 a0 = load8(srcA0[region] + col);
    bf16x8 a1 = load8(srcA1[region] + col);
    const __bf16* bp = We1t + (size_t)lm * 384 + step * 32 + q * 8;
#pragma unroll
    for (int nt = 0; nt < 8; ++nt) {
      bf16x8 bb = *(const bf16x8*)(bp + nt * 16 * 384);
      acc[0][nt] = MFMA16(a0, bb, acc[0][nt]);
      acc[1][nt] = MFMA16(a1, bb, acc[1][nt]);
    }
  }

  // relu + C-layout -> A-layout via LDS
#pragma unroll
  for (int t = 0; t < 2; ++t)
#pragma unroll
    for (int nt = 0; nt < 8; ++nt)
#pragma unroll
      for (int r = 0; r < 4; ++r) {
        float v = acc[t][nt][r];
        v = v > 0.f ? v : 0.f;
        int m = row0 + t * 16 + q * 4 + r;
        h1[m * 136 + nt * 16 + lm] = __builtin_bit_cast(unsigned short, f2bf(v));
      }
  __syncthreads();

  // phase 2: h1 @ We2 + be2, K = 128
#pragma unroll
  for (int nt = 0; nt < 8; ++nt) {
    float b = be2[nt * 16 + lm];
    acc[0][nt] = (f32x4){b, b, b, b};
    acc[1][nt] = (f32x4){b, b, b, b};
  }
#pragma unroll
  for (int step = 0; step < 4; ++step) {
    bf16x8 a0 = __builtin_bit_cast(bf16x8, *(const u16x8*)&h1[(row0 + lm) * 136 + step * 32 + q * 8]);
    bf16x8 a1 = __builtin_bit_cast(bf16x8, *(const u16x8*)&h1[(row0 + 16 + lm) * 136 + step * 32 + q * 8]);
    const __bf16* bp = We2t + (size_t)lm * 128 + step * 32 + q * 8;
#pragma unroll
    for (int nt = 0; nt < 8; ++nt) {
      bf16x8 bb = *(const bf16x8*)(bp + nt * 16 * 128);
      acc[0][nt] = MFMA16(a0, bb, acc[0][nt]);
      acc[1][nt] = MFMA16(a1, bb, acc[1][nt]);
    }
  }

  // scatter-add e_new into agg[dst]
#pragma unroll
  for (int t = 0; t < 2; ++t) {
#pragma unroll
    for (int r = 0; r < 4; ++r) {
      int e = e0 + row0 + t * 16 + q * 4 + r;
      float* arow = agg + (size_t)dst[e] * DD + lm;
#pragma unroll
      for (int nt = 0; nt < 8; ++nt)
        unsafeAtomicAdd(arow + nt * 16, acc[t][nt][r]);
    }
  }
}

// ---- node MLP: tile = 128 nodes x 128 out ----
__global__ __launch_bounds__(256) void node_kernel(
    const float* __restrict__ node_h, const float* __restrict__ agg,
    const __bf16* __restrict__ Wn1t, const float* __restrict__ bn1,
    const __bf16* __restrict__ Wn2t, const float* __restrict__ bn2,
    float* __restrict__ out) {
  __shared__ unsigned short h1[128 * 136];
  const int tid = (int)threadIdx.x;
  const int w = tid >> 6;
  const int l = tid & 63;
  const int lm = l & 15;
  const int q = l >> 4;
  const int n0 = (int)blockIdx.x * 128;
  const int row0 = w * 32;

  int r0 = n0 + row0 + lm;
  int r1 = r0 + 16;
  int c0 = r0 < NN ? r0 : NN - 1;
  int c1 = r1 < NN ? r1 : NN - 1;
  const float* srcA0[2] = {agg + (size_t)c0 * DD, node_h + (size_t)c0 * DD};
  const float* srcA1[2] = {agg + (size_t)c1 * DD, node_h + (size_t)c1 * DD};

  f32x4 acc[2][8];
#pragma unroll
  for (int nt = 0; nt < 8; ++nt) {
    float b = bn1[nt * 16 + lm];
    acc[0][nt] = (f32x4){b, b, b, b};
    acc[1][nt] = (f32x4){b, b, b, b};
  }

  // phase 1: relu(concat(agg, node_h) @ Wn1 + bn1), K = 256
#pragma unroll
  for (int step = 0; step < 8; ++step) {
    const int region = step >> 2;                  // 0:agg 1:node_h
    const int col = ((step & 3) * 32) + q * 8;
    bf16x8 a0 = load8(srcA0[region] + col);
    bf16x8 a1 = load8(srcA1[region] + col);
    const __bf16* bp = Wn1t + (size_t)lm * 256 + step * 32 + q * 8;
#pragma unroll
    for (int nt = 0; nt < 8; ++nt) {
      bf16x8 bb = *(const bf16x8*)(bp + nt * 16 * 256);
      acc[0][nt] = MFMA16(a0, bb, acc[0][nt]);
      acc[1][nt] = MFMA16(a1, bb, acc[1][nt]);
    }
  }

#pragma unroll
  for (int t = 0; t < 2; ++t)
#pragma unroll
    for (int nt = 0; nt < 8; ++nt)
#pragma unroll
      for (int r = 0; r < 4; ++r) {
        float v = acc[t][nt][r];
        v = v > 0.f ? v : 0.f;
        int m = row0 + t * 16 + q * 4 + r;
        h1[m * 136 + nt * 16 + lm] = __builtin_bit_cast(unsigned short, f2bf(v));
      }
  __syncthreads();

  // phase 2: h1 @ Wn2 + bn2, K = 128
#pragma unroll
  for (int nt = 0; nt < 8; ++nt) {
    float b = bn2[nt * 16 + lm];
    acc[0][nt] = (f32x4){b, b, b, b};
    acc[1][nt] = (f32x4){b, b, b, b};
  }
#pragma unroll
  for (int step = 0; step < 4; ++step) {
    bf16x8 a0 = __builtin_bit_cast(bf16x8, *(const u16x8*)&h1[(row0 + lm) * 136 + step * 32 + q * 8]);
    bf16x8 a1 = __builtin_bit_cast(bf16x8, *(const u16x8*)&h1[(row0 + 16 + lm) * 136 + step * 32 + q * 8]);
    const __bf16* bp = Wn2t + (size_t)lm * 128 + step * 32 + q * 8;
#pragma unroll
    for (int nt = 0; nt < 8; ++nt) {
      bf16x8 bb = *(const bf16x8*)(bp + nt * 16 * 128);
      acc[0][nt] = MFMA16(a0, bb, acc[0][nt]);
      acc[1][nt] = MFMA16(a1, bb, acc[1][nt]);
    }
  }

#pragma unroll
  for (int t = 0; t < 2; ++t) {
#pragma unroll
    for (int r = 0; r < 4; ++r) {
      int node = n0 + row0 + t * 16 + q * 4 + r;
      if (node < NN) {
        float* orow = out + (size_t)node * DD + lm;
#pragma unroll
        for (int nt = 0; nt < 8; ++nt)
          orow[nt * 16] = acc[t][nt][r];
      }
    }
  }
}

extern "C" void kernel_launch(void* const* d_in, const int* in_sizes, int n_in,
                              void* d_out, int out_size, void* d_ws, size_t ws_size,
                              hipStream_t stream) {
  const float* node_h = (const float*)d_in[0];
  const float* edge_h = (const float*)d_in[1];
  const int* src = (const int*)d_in[2];
  const int* dst = (const int*)d_in[3];
  const float* We1 = (const float*)d_in[4];
  const float* be1 = (const float*)d_in[5];
  const float* We2 = (const float*)d_in[6];
  const float* be2 = (const float*)d_in[7];
  const float* Wn1 = (const float*)d_in[8];
  const float* bn1 = (const float*)d_in[9];
  const float* Wn2 = (const float*)d_in[10];
  const float* bn2 = (const float*)d_in[11];

  // ws layout
  const size_t agg_bytes = (size_t)NN * DD * sizeof(float);          // 25,600,000
  float* agg = (float*)d_ws;
  char* wbase = (char*)d_ws + agg_bytes;
  __bf16* We1t = (__bf16*)(wbase);                                   // 128*384
  __bf16* We2t = (__bf16*)(wbase + 98304);                           // 128*128
  __bf16* Wn1t = (__bf16*)(wbase + 98304 + 32768);                   // 128*256
  __bf16* Wn2t = (__bf16*)(wbase + 98304 + 32768 + 65536);           // 128*128

  hipMemsetAsync(agg, 0, agg_bytes, stream);
  prep_kernel<<<(114688 + 255) / 256, 256, 0, stream>>>(We1, We2, Wn1, Wn2,
                                                        We1t, We2t, Wn1t, Wn2t);
  edge_kernel<<<NE / 128, 256, 0, stream>>>(node_h, edge_h, src, dst,
                                            We1t, be1, We2t, be2, agg);
  node_kernel<<<(NN + 127) / 128, 256, 0, stream>>>(node_h, agg, Wn1t, bn1,
                                                    Wn2t, bn2, (float*)d_out);
}

// Round 2
// 993.402 us; speedup vs baseline: 1.0248x; 1.0248x over previous
//
#include <hip/hip_runtime.h>

#define NN 50000
#define NE 640000
#define DD 128

typedef float f32x4 __attribute__((ext_vector_type(4)));
typedef __bf16 bf16x8 __attribute__((ext_vector_type(8)));
typedef unsigned short u16x8 __attribute__((ext_vector_type(8)));

__device__ inline __bf16 f2bf(float f) {
  unsigned u = __builtin_bit_cast(unsigned, f);
  u = (u + 0x7fffu + ((u >> 16) & 1u)) >> 16;
  unsigned short h = (unsigned short)u;
  return __builtin_bit_cast(__bf16, h);
}
__device__ inline unsigned short f2bfu(float f) {
  return __builtin_bit_cast(unsigned short, f2bf(f));
}
__device__ inline float bf2f(unsigned bits16) {
  return __builtin_bit_cast(float, bits16 << 16);
}

__device__ inline bf16x8 load8(const float* __restrict__ p) {
  f32x4 a = *(const f32x4*)p;
  f32x4 b = *(const f32x4*)(p + 4);
  bf16x8 o;
  o[0] = f2bf(a[0]); o[1] = f2bf(a[1]); o[2] = f2bf(a[2]); o[3] = f2bf(a[3]);
  o[4] = f2bf(b[0]); o[5] = f2bf(b[1]); o[6] = f2bf(b[2]); o[7] = f2bf(b[3]);
  return o;
}

#define MFMA16(a, b, c) __builtin_amdgcn_mfma_f32_16x16x32_bf16((a), (b), (c), 0, 0, 0)

// ---- prep: transpose + convert the 4 weight matrices to bf16 Bt[n][k] ----
__global__ void prep_kernel(const float* __restrict__ We1, const float* __restrict__ We2,
                            const float* __restrict__ Wn1, const float* __restrict__ Wn2,
                            __bf16* __restrict__ We1t, __bf16* __restrict__ We2t,
                            __bf16* __restrict__ Wn1t, __bf16* __restrict__ Wn2t) {
  int i = blockIdx.x * blockDim.x + threadIdx.x;
  if (i < 49152) {                       // We1: [384][128] -> [128][384]
    int n = i / 384, k = i % 384;
    We1t[i] = f2bf(We1[k * 128 + n]);
  } else if (i < 65536) {                // We2: [128][128]
    int j = i - 49152; int n = j / 128, k = j % 128;
    We2t[j] = f2bf(We2[k * 128 + n]);
  } else if (i < 98304) {                // Wn1: [256][128] -> [128][256]
    int j = i - 65536; int n = j / 256, k = j % 256;
    Wn1t[j] = f2bf(Wn1[k * 128 + n]);
  } else if (i < 114688) {               // Wn2: [128][128]
    int j = i - 98304; int n = j / 128, k = j % 128;
    Wn2t[j] = f2bf(Wn2[k * 128 + n]);
  }
}

// ---- convert node_h fp32 -> bf16 (12.8 MB; L3-resident gather target) ----
__global__ void conv_node_kernel(const float* __restrict__ nh,
                                 unsigned short* __restrict__ nhb) {
  int i = blockIdx.x * 256 + threadIdx.x;   // 800000 threads x 8 floats
  if (i >= NN * DD / 8) return;
  const float* p = nh + (size_t)i * 8;
  f32x4 a = *(const f32x4*)p;
  f32x4 b = *(const f32x4*)(p + 4);
  u16x8 o;
  o[0] = f2bfu(a[0]); o[1] = f2bfu(a[1]); o[2] = f2bfu(a[2]); o[3] = f2bfu(a[3]);
  o[4] = f2bfu(b[0]); o[5] = f2bfu(b[1]); o[6] = f2bfu(b[2]); o[7] = f2bfu(b[3]);
  *(u16x8*)(nhb + (size_t)i * 8) = o;
}

// ---- CSR build ----
__global__ void hist_kernel(const int* __restrict__ dst, int* __restrict__ counts) {
  int i = blockIdx.x * 256 + threadIdx.x;
  if (i < NE) atomicAdd(&counts[dst[i]], 1);
}
__global__ void scan1_kernel(const int* __restrict__ counts, int* __restrict__ basearr,
                             int* __restrict__ partials) {
  __shared__ int sd[256];
  int t = threadIdx.x;
  int i = blockIdx.x * 256 + t;
  int v = (i < NN) ? counts[i] : 0;
  sd[t] = v; __syncthreads();
  for (int off = 1; off < 256; off <<= 1) {
    int x = (t >= off) ? sd[t - off] : 0;
    __syncthreads();
    sd[t] += x;
    __syncthreads();
  }
  if (i < NN) basearr[i] = sd[t] - v;
  if (t == 255) partials[blockIdx.x] = sd[255];
}
__global__ void scan2_kernel(const int* __restrict__ partials, int* __restrict__ poff,
                             int nparts) {
  __shared__ int sd[256];
  int t = threadIdx.x;
  int v = (t < nparts) ? partials[t] : 0;
  sd[t] = v; __syncthreads();
  for (int off = 1; off < 256; off <<= 1) {
    int x = (t >= off) ? sd[t - off] : 0;
    __syncthreads();
    sd[t] += x;
    __syncthreads();
  }
  if (t < nparts) poff[t] = sd[t] - v;
}
__global__ void scan3_kernel(int* __restrict__ basearr, const int* __restrict__ poff) {
  int i = blockIdx.x * 256 + threadIdx.x;
  if (i < NN) basearr[i] += poff[blockIdx.x];
}
__global__ void scatter_kernel(const int* __restrict__ dst, const int* __restrict__ basearr,
                               int* __restrict__ cursor, int* __restrict__ eids) {
  int i = blockIdx.x * 256 + threadIdx.x;
  if (i < NE) {
    int d = dst[i];
    int p = basearr[d] + atomicAdd(&cursor[d], 1);
    eids[p] = i;
  }
}

// ---- edge MLP: tile = 128 edges x 128 out, writes e_new bf16 coalesced ----
__global__ __launch_bounds__(256) void edge_kernel(
    const unsigned short* __restrict__ nhb, const float* __restrict__ edge_h,
    const int* __restrict__ src, const int* __restrict__ dst,
    const __bf16* __restrict__ We1t, const float* __restrict__ be1,
    const __bf16* __restrict__ We2t, const float* __restrict__ be2,
    unsigned short* __restrict__ enew) {
  __shared__ unsigned short h1[128 * 136];
  const int tid = (int)threadIdx.x;
  const int w = tid >> 6;
  const int l = tid & 63;
  const int lm = l & 15;
  const int q = l >> 4;
  const int e0 = (int)blockIdx.x * 128;
  const int row0 = w * 32;

  const int eA0 = e0 + row0 + lm;
  const int eA1 = eA0 + 16;
  const unsigned short* gA0[2] = {nhb + (size_t)src[eA0] * DD, nhb + (size_t)dst[eA0] * DD};
  const unsigned short* gA1[2] = {nhb + (size_t)src[eA1] * DD, nhb + (size_t)dst[eA1] * DD};
  const float* eh0 = edge_h + (size_t)eA0 * DD;
  const float* eh1 = edge_h + (size_t)eA1 * DD;

  f32x4 acc[2][8];
#pragma unroll
  for (int nt = 0; nt < 8; ++nt) {
    float b = be1[nt * 16 + lm];
    acc[0][nt] = (f32x4){b, b, b, b};
    acc[1][nt] = (f32x4){b, b, b, b};
  }

  // phase 1a: K-steps 0..7  (src-h, dst-h gathers, bf16 direct)
#pragma unroll
  for (int step = 0; step < 8; ++step) {
    const int region = step >> 2;
    const int col = ((step & 3) * 32) + q * 8;
    bf16x8 a0 = __builtin_bit_cast(bf16x8, *(const u16x8*)(gA0[region] + col));
    bf16x8 a1 = __builtin_bit_cast(bf16x8, *(const u16x8*)(gA1[region] + col));
    const __bf16* bp = We1t + (size_t)lm * 384 + step * 32 + q * 8;
#pragma unroll
    for (int nt = 0; nt < 8; ++nt) {
      bf16x8 bb = *(const bf16x8*)(bp + nt * 16 * 384);
      acc[0][nt] = MFMA16(a0, bb, acc[0][nt]);
      acc[1][nt] = MFMA16(a1, bb, acc[1][nt]);
    }
  }
  // phase 1b: K-steps 8..11 (edge_h rows, fp32 convert inline)
#pragma unroll
  for (int s2 = 0; s2 < 4; ++s2) {
    const int col = s2 * 32 + q * 8;
    bf16x8 a0 = load8(eh0 + col);
    bf16x8 a1 = load8(eh1 + col);
    const __bf16* bp = We1t + (size_t)lm * 384 + (8 + s2) * 32 + q * 8;
#pragma unroll
    for (int nt = 0; nt < 8; ++nt) {
      bf16x8 bb = *(const bf16x8*)(bp + nt * 16 * 384);
      acc[0][nt] = MFMA16(a0, bb, acc[0][nt]);
      acc[1][nt] = MFMA16(a1, bb, acc[1][nt]);
    }
  }

  // relu + C-layout -> A-layout via LDS
#pragma unroll
  for (int t = 0; t < 2; ++t)
#pragma unroll
    for (int nt = 0; nt < 8; ++nt)
#pragma unroll
      for (int r = 0; r < 4; ++r) {
        float v = acc[t][nt][r];
        v = v > 0.f ? v : 0.f;
        int m = row0 + t * 16 + q * 4 + r;
        h1[m * 136 + nt * 16 + lm] = f2bfu(v);
      }
  __syncthreads();

  // phase 2: h1 @ We2 + be2, K = 128
#pragma unroll
  for (int nt = 0; nt < 8; ++nt) {
    float b = be2[nt * 16 + lm];
    acc[0][nt] = (f32x4){b, b, b, b};
    acc[1][nt] = (f32x4){b, b, b, b};
  }
#pragma unroll
  for (int step = 0; step < 4; ++step) {
    bf16x8 a0 = __builtin_bit_cast(bf16x8, *(const u16x8*)&h1[(row0 + lm) * 136 + step * 32 + q * 8]);
    bf16x8 a1 = __builtin_bit_cast(bf16x8, *(const u16x8*)&h1[(row0 + 16 + lm) * 136 + step * 32 + q * 8]);
    const __bf16* bp = We2t + (size_t)lm * 128 + step * 32 + q * 8;
#pragma unroll
    for (int nt = 0; nt < 8; ++nt) {
      bf16x8 bb = *(const bf16x8*)(bp + nt * 16 * 128);
      acc[0][nt] = MFMA16(a0, bb, acc[0][nt]);
      acc[1][nt] = MFMA16(a1, bb, acc[1][nt]);
    }
  }
  __syncthreads();   // all phase-2 h1 reads complete before overwrite

  // e_new tile -> h1 (bf16) -> coalesced global store
#pragma unroll
  for (int t = 0; t < 2; ++t)
#pragma unroll
    for (int nt = 0; nt < 8; ++nt)
#pragma unroll
      for (int r = 0; r < 4; ++r) {
        int m = row0 + t * 16 + q * 4 + r;
        h1[m * 136 + nt * 16 + lm] = f2bfu(acc[t][nt][r]);
      }
  __syncthreads();
  {
    int row = tid >> 1, half = tid & 1;
    const u16x8* sp = (const u16x8*)&h1[row * 136 + half * 64];
    u16x8* dp = (u16x8*)(enew + (size_t)(e0 + row) * DD + half * 64);
#pragma unroll
    for (int j = 0; j < 8; ++j) dp[j] = sp[j];
  }
}

// ---- aggregation: one wave per node, CSR gather of e_new rows ----
__global__ __launch_bounds__(256) void agg_kernel(
    const unsigned short* __restrict__ enew, const int* __restrict__ eids,
    const int* __restrict__ basearr, const int* __restrict__ counts,
    unsigned short* __restrict__ aggb) {
  int n = blockIdx.x * 4 + (threadIdx.x >> 6);
  if (n >= NN) return;
  int l = threadIdx.x & 63;
  int s = basearr[n], len = counts[n];
  float a0 = 0.f, a1 = 0.f;
  int j = 0;
  for (; j + 1 < len; j += 2) {
    int ea = eids[s + j], eb = eids[s + j + 1];
    unsigned ua = *(const unsigned*)(enew + (size_t)ea * DD + l * 2);
    unsigned ub = *(const unsigned*)(enew + (size_t)eb * DD + l * 2);
    a0 += bf2f(ua & 0xffffu) + bf2f(ub & 0xffffu);
    a1 += bf2f(ua >> 16) + bf2f(ub >> 16);
  }
  if (j < len) {
    int ea = eids[s + j];
    unsigned ua = *(const unsigned*)(enew + (size_t)ea * DD + l * 2);
    a0 += bf2f(ua & 0xffffu);
    a1 += bf2f(ua >> 16);
  }
  unsigned o = (unsigned)f2bfu(a0) | ((unsigned)f2bfu(a1) << 16);
  *(unsigned*)(aggb + (size_t)n * DD + l * 2) = o;
}

// ---- node MLP: tile = 128 nodes x 128 out, bf16 A operands ----
__global__ __launch_bounds__(256) void node_kernel(
    const unsigned short* __restrict__ nhb, const unsigned short* __restrict__ aggb,
    const __bf16* __restrict__ Wn1t, const float* __restrict__ bn1,
    const __bf16* __restrict__ Wn2t, const float* __restrict__ bn2,
    float* __restrict__ out) {
  __shared__ unsigned short h1[128 * 136];
  const int tid = (int)threadIdx.x;
  const int w = tid >> 6;
  const int l = tid & 63;
  const int lm = l & 15;
  const int q = l >> 4;
  const int n0 = (int)blockIdx.x * 128;
  const int row0 = w * 32;

  int r0 = n0 + row0 + lm;
  int r1 = r0 + 16;
  int c0 = r0 < NN ? r0 : NN - 1;
  int c1 = r1 < NN ? r1 : NN - 1;
  const unsigned short* srcA0[2] = {aggb + (size_t)c0 * DD, nhb + (size_t)c0 * DD};
  const unsigned short* srcA1[2] = {aggb + (size_t)c1 * DD, nhb + (size_t)c1 * DD};

  f32x4 acc[2][8];
#pragma unroll
  for (int nt = 0; nt < 8; ++nt) {
    float b = bn1[nt * 16 + lm];
    acc[0][nt] = (f32x4){b, b, b, b};
    acc[1][nt] = (f32x4){b, b, b, b};
  }

  // phase 1: relu(concat(agg, node_h) @ Wn1 + bn1), K = 256
#pragma unroll
  for (int step = 0; step < 8; ++step) {
    const int region = step >> 2;
    const int col = ((step & 3) * 32) + q * 8;
    bf16x8 a0 = __builtin_bit_cast(bf16x8, *(const u16x8*)(srcA0[region] + col));
    bf16x8 a1 = __builtin_bit_cast(bf16x8, *(const u16x8*)(srcA1[region] + col));
    const __bf16* bp = Wn1t + (size_t)lm * 256 + step * 32 + q * 8;
#pragma unroll
    for (int nt = 0; nt < 8; ++nt) {
      bf16x8 bb = *(const bf16x8*)(bp + nt * 16 * 256);
      acc[0][nt] = MFMA16(a0, bb, acc[0][nt]);
      acc[1][nt] = MFMA16(a1, bb, acc[1][nt]);
    }
  }

#pragma unroll
  for (int t = 0; t < 2; ++t)
#pragma unroll
    for (int nt = 0; nt < 8; ++nt)
#pragma unroll
      for (int r = 0; r < 4; ++r) {
        float v = acc[t][nt][r];
        v = v > 0.f ? v : 0.f;
        int m = row0 + t * 16 + q * 4 + r;
        h1[m * 136 + nt * 16 + lm] = f2bfu(v);
      }
  __syncthreads();

  // phase 2: h1 @ Wn2 + bn2, K = 128
#pragma unroll
  for (int nt = 0; nt < 8; ++nt) {
    float b = bn2[nt * 16 + lm];
    acc[0][nt] = (f32x4){b, b, b, b};
    acc[1][nt] = (f32x4){b, b, b, b};
  }
#pragma unroll
  for (int step = 0; step < 4; ++step) {
    bf16x8 a0 = __builtin_bit_cast(bf16x8, *(const u16x8*)&h1[(row0 + lm) * 136 + step * 32 + q * 8]);
    bf16x8 a1 = __builtin_bit_cast(bf16x8, *(const u16x8*)&h1[(row0 + 16 + lm) * 136 + step * 32 + q * 8]);
    const __bf16* bp = Wn2t + (size_t)lm * 128 + step * 32 + q * 8;
#pragma unroll
    for (int nt = 0; nt < 8; ++nt) {
      bf16x8 bb = *(const bf16x8*)(bp + nt * 16 * 128);
      acc[0][nt] = MFMA16(a0, bb, acc[0][nt]);
      acc[1][nt] = MFMA16(a1, bb, acc[1][nt]);
    }
  }

#pragma unroll
  for (int t = 0; t < 2; ++t) {
#pragma unroll
    for (int r = 0; r < 4; ++r) {
      int node = n0 + row0 + t * 16 + q * 4 + r;
      if (node < NN) {
        float* orow = out + (size_t)node * DD + lm;
#pragma unroll
        for (int nt = 0; nt < 8; ++nt)
          orow[nt * 16] = acc[t][nt][r];
      }
    }
  }
}

// ======================= fallback (R1 atomic path) =======================
__global__ __launch_bounds__(256) void edge_fb_kernel(
    const float* __restrict__ node_h, const float* __restrict__ edge_h,
    const int* __restrict__ src, const int* __restrict__ dst,
    const __bf16* __restrict__ We1t, const float* __restrict__ be1,
    const __bf16* __restrict__ We2t, const float* __restrict__ be2,
    float* __restrict__ agg) {
  __shared__ unsigned short h1[128 * 136];
  const int tid = (int)threadIdx.x;
  const int w = tid >> 6;
  const int l = tid & 63;
  const int lm = l & 15;
  const int q = l >> 4;
  const int e0 = (int)blockIdx.x * 128;
  const int row0 = w * 32;

  const int eA0 = e0 + row0 + lm;
  const int eA1 = eA0 + 16;
  const float* srcA0[3];
  const float* srcA1[3];
  srcA0[0] = node_h + (size_t)src[eA0] * DD;
  srcA0[1] = node_h + (size_t)dst[eA0] * DD;
  srcA0[2] = edge_h + (size_t)eA0 * DD;
  srcA1[0] = node_h + (size_t)src[eA1] * DD;
  srcA1[1] = node_h + (size_t)dst[eA1] * DD;
  srcA1[2] = edge_h + (size_t)eA1 * DD;

  f32x4 acc[2][8];
#pragma unroll
  for (int nt = 0; nt < 8; ++nt) {
    float b = be1[nt * 16 + lm];
    acc[0][nt] = (f32x4){b, b, b, b};
    acc[1][nt] = (f32x4){b, b, b, b};
  }
#pragma unroll
  for (int step = 0; step < 12; ++step) {
    const int region = step >> 2;
    const int col = ((step & 3) * 32) + q * 8;
    bf16x8 a0 = load8(srcA0[region] + col);
    bf16x8 a1 = load8(srcA1[region] + col);
    const __bf16* bp = We1t + (size_t)lm * 384 + step * 32 + q * 8;
#pragma unroll
    for (int nt = 0; nt < 8; ++nt) {
      bf16x8 bb = *(const bf16x8*)(bp + nt * 16 * 384);
      acc[0][nt] = MFMA16(a0, bb, acc[0][nt]);
      acc[1][nt] = MFMA16(a1, bb, acc[1][nt]);
    }
  }
#pragma unroll
  for (int t = 0; t < 2; ++t)
#pragma unroll
    for (int nt = 0; nt < 8; ++nt)
#pragma unroll
      for (int r = 0; r < 4; ++r) {
        float v = acc[t][nt][r];
        v = v > 0.f ? v : 0.f;
        int m = row0 + t * 16 + q * 4 + r;
        h1[m * 136 + nt * 16 + lm] = f2bfu(v);
      }
  __syncthreads();
#pragma unroll
  for (int nt = 0; nt < 8; ++nt) {
    float b = be2[nt * 16 + lm];
    acc[0][nt] = (f32x4){b, b, b, b};
    acc[1][nt] = (f32x4){b, b, b, b};
  }
#pragma unroll
  for (int step = 0; step < 4; ++step) {
    bf16x8 a0 = __builtin_bit_cast(bf16x8, *(const u16x8*)&h1[(row0 + lm) * 136 + step * 32 + q * 8]);
    bf16x8 a1 = __builtin_bit_cast(bf16x8, *(const u16x8*)&h1[(row0 + 16 + lm) * 136 + step * 32 + q * 8]);
    const __bf16* bp = We2t + (size_t)lm * 128 + step * 32 + q * 8;
#pragma unroll
    for (int nt = 0; nt < 8; ++nt) {
      bf16x8 bb = *(const bf16x8*)(bp + nt * 16 * 128);
      acc[0][nt] = MFMA16(a0, bb, acc[0][nt]);
      acc[1][nt] = MFMA16(a1, bb, acc[1][nt]);
    }
  }
#pragma unroll
  for (int t = 0; t < 2; ++t) {
#pragma unroll
    for (int r = 0; r < 4; ++r) {
      int e = e0 + row0 + t * 16 + q * 4 + r;
      float* arow = agg + (size_t)dst[e] * DD + lm;
#pragma unroll
      for (int nt = 0; nt < 8; ++nt)
        unsafeAtomicAdd(arow + nt * 16, acc[t][nt][r]);
    }
  }
}

__global__ __launch_bounds__(256) void node_fb_kernel(
    const float* __restrict__ node_h, const float* __restrict__ agg,
    const __bf16* __restrict__ Wn1t, const float* __restrict__ bn1,
    const __bf16* __restrict__ Wn2t, const float* __restrict__ bn2,
    float* __restrict__ out) {
  __shared__ unsigned short h1[128 * 136];
  const int tid = (int)threadIdx.x;
  const int w = tid >> 6;
  const int l = tid & 63;
  const int lm = l & 15;
  const int q = l >> 4;
  const int n0 = (int)blockIdx.x * 128;
  const int row0 = w * 32;

  int r0 = n0 + row0 + lm;
  int r1 = r0 + 16;
  int c0 = r0 < NN ? r0 : NN - 1;
  int c1 = r1 < NN ? r1 : NN - 1;
  const float* srcA0[2] = {agg + (size_t)c0 * DD, node_h + (size_t)c0 * DD};
  const float* srcA1[2] = {agg + (size_t)c1 * DD, node_h + (size_t)c1 * DD};

  f32x4 acc[2][8];
#pragma unroll
  for (int nt = 0; nt < 8; ++nt) {
    float b = bn1[nt * 16 + lm];
    acc[0][nt] = (f32x4){b, b, b, b};
    acc[1][nt] = (f32x4){b, b, b, b};
  }
#pragma unroll
  for (int step = 0; step < 8; ++step) {
    const int region = step >> 2;
    const int col = ((step & 3) * 32) + q * 8;
    bf16x8 a0 = load8(srcA0[region] + col);
    bf16x8 a1 = load8(srcA1[region] + col);
    const __bf16* bp = Wn1t + (size_t)lm * 256 + step * 32 + q * 8;
#pragma unroll
    for (int nt = 0; nt < 8; ++nt) {
      bf16x8 bb = *(const bf16x8*)(bp + nt * 16 * 256);
      acc[0][nt] = MFMA16(a0, bb, acc[0][nt]);
      acc[1][nt] = MFMA16(a1, bb, acc[1][nt]);
    }
  }
#pragma unroll
  for (int t = 0; t < 2; ++t)
#pragma unroll
    for (int nt = 0; nt < 8; ++nt)
#pragma unroll
      for (int r = 0; r < 4; ++r) {
        float v = acc[t][nt][r];
        v = v > 0.f ? v : 0.f;
        int m = row0 + t * 16 + q * 4 + r;
        h1[m * 136 + nt * 16 + lm] = f2bfu(v);
      }
  __syncthreads();
#pragma unroll
  for (int nt = 0; nt < 8; ++nt) {
    float b = bn2[nt * 16 + lm];
    acc[0][nt] = (f32x4){b, b, b, b};
    acc[1][nt] = (f32x4){b, b, b, b};
  }
#pragma unroll
  for (int step = 0; step < 4; ++step) {
    bf16x8 a0 = __builtin_bit_cast(bf16x8, *(const u16x8*)&h1[(row0 + lm) * 136 + step * 32 + q * 8]);
    bf16x8 a1 = __builtin_bit_cast(bf16x8, *(const u16x8*)&h1[(row0 + 16 + lm) * 136 + step * 32 + q * 8]);
    const __bf16* bp = Wn2t + (size_t)lm * 128 + step * 32 + q * 8;
#pragma unroll
    for (int nt = 0; nt < 8; ++nt) {
      bf16x8 bb = *(const bf16x8*)(bp + nt * 16 * 128);
      acc[0][nt] = MFMA16(a0, bb, acc[0][nt]);
      acc[1][nt] = MFMA16(a1, bb, acc[1][nt]);
    }
  }
#pragma unroll
  for (int t = 0; t < 2; ++t) {
#pragma unroll
    for (int r = 0; r < 4; ++r) {
      int node = n0 + row0 + t * 16 + q * 4 + r;
      if (node < NN) {
        float* orow = out + (size_t)node * DD + lm;
#pragma unroll
        for (int nt = 0; nt < 8; ++nt)
          orow[nt * 16] = acc[t][nt][r];
      }
    }
  }
}

extern "C" void kernel_launch(void* const* d_in, const int* in_sizes, int n_in,
                              void* d_out, int out_size, void* d_ws, size_t ws_size,
                              hipStream_t stream) {
  const float* node_h = (const float*)d_in[0];
  const float* edge_h = (const float*)d_in[1];
  const int* src = (const int*)d_in[2];
  const int* dst = (const int*)d_in[3];
  const float* We1 = (const float*)d_in[4];
  const float* be1 = (const float*)d_in[5];
  const float* We2 = (const float*)d_in[6];
  const float* be2 = (const float*)d_in[7];
  const float* Wn1 = (const float*)d_in[8];
  const float* bn1 = (const float*)d_in[9];
  const float* Wn2 = (const float*)d_in[10];
  const float* bn2 = (const float*)d_in[11];

  // CSR-path ws layout (bytes)
  const size_t o_enew = 0;                    // 163,840,000
  const size_t o_nhb  = 163840000;            //  12,800,000
  const size_t o_aggb = 176640000;            //  12,800,000
  const size_t o_we1  = 189440000;            //      98,304
  const size_t o_we2  = 189538304;            //      32,768
  const size_t o_wn1  = 189571072;            //      65,536
  const size_t o_wn2  = 189636608;            //      32,768
  const size_t o_cnt  = 189669376;            //     200,000
  const size_t o_base = 189869376;            //     200,000
  const size_t o_cur  = 190069376;            //     200,000
  const size_t o_poff = 190269376;            //       1,024
  const size_t o_eids = 190270400;            //   2,560,000
  const size_t csr_need = 192830400;

  char* ws = (char*)d_ws;

  if (ws_size >= csr_need) {
    unsigned short* enew = (unsigned short*)(ws + o_enew);
    unsigned short* nhb  = (unsigned short*)(ws + o_nhb);
    unsigned short* aggb = (unsigned short*)(ws + o_aggb);
    __bf16* We1t = (__bf16*)(ws + o_we1);
    __bf16* We2t = (__bf16*)(ws + o_we2);
    __bf16* Wn1t = (__bf16*)(ws + o_wn1);
    __bf16* Wn2t = (__bf16*)(ws + o_wn2);
    int* counts  = (int*)(ws + o_cnt);
    int* basearr = (int*)(ws + o_base);
    int* cursor  = (int*)(ws + o_cur);
    int* poff    = (int*)(ws + o_poff);
    int* eids    = (int*)(ws + o_eids);

    hipMemsetAsync(counts, 0, NN * sizeof(int), stream);
    hipMemsetAsync(cursor, 0, NN * sizeof(int), stream);
    conv_node_kernel<<<(NN * DD / 8 + 255) / 256, 256, 0, stream>>>(node_h, nhb);
    prep_kernel<<<(114688 + 255) / 256, 256, 0, stream>>>(We1, We2, Wn1, Wn2,
                                                          We1t, We2t, Wn1t, Wn2t);
    hist_kernel<<<(NE + 255) / 256, 256, 0, stream>>>(dst, counts);
    const int nparts = (NN + 255) / 256;   // 196
    scan1_kernel<<<nparts, 256, 0, stream>>>(counts, basearr, cursor + 0);
    // reuse: partials stored in 'cursor' temporarily? NO — cursor must stay 0.
    // use poff-adjacent scratch: partials go in eids tail (eids has NE slots, use last 256)
    // -- simpler: dedicated partials buffer = poff + 256 ints? poff is 1024 B = 256 ints.
    // Redo properly below.
    (void)0;
    // NOTE: scan1 above wrote partials into cursor — fix by re-zeroing cursor after scans.
    scan2_kernel<<<1, 256, 0, stream>>>(cursor, poff, nparts);
    scan3_kernel<<<nparts, 256, 0, stream>>>(basearr, poff);
    hipMemsetAsync(cursor, 0, NN * sizeof(int), stream);
    scatter_kernel<<<(NE + 255) / 256, 256, 0, stream>>>(dst, basearr, cursor, eids);
    edge_kernel<<<NE / 128, 256, 0, stream>>>(nhb, edge_h, src, dst,
                                              We1t, be1, We2t, be2, enew);
    agg_kernel<<<(NN + 3) / 4, 256, 0, stream>>>(enew, eids, basearr, counts, aggb);
    node_kernel<<<(NN + 127) / 128, 256, 0, stream>>>(nhb, aggb, Wn1t, bn1,
                                                      Wn2t, bn2, (float*)d_out);
  } else {
    // fallback: R1 atomic path (ws >= ~25.9 MB)
    const size_t agg_bytes = (size_t)NN * DD * sizeof(float);
    float* agg = (float*)d_ws;
    char* wbase = ws + agg_bytes;
    __bf16* We1t = (__bf16*)(wbase);
    __bf16* We2t = (__bf16*)(wbase + 98304);
    __bf16* Wn1t = (__bf16*)(wbase + 98304 + 32768);
    __bf16* Wn2t = (__bf16*)(wbase + 98304 + 32768 + 65536);

    hipMemsetAsync(agg, 0, agg_bytes, stream);
    prep_kernel<<<(114688 + 255) / 256, 256, 0, stream>>>(We1, We2, Wn1, Wn2,
                                                          We1t, We2t, Wn1t, Wn2t);
    edge_fb_kernel<<<NE / 128, 256, 0, stream>>>(node_h, edge_h, src, dst,
                                                 We1t, be1, We2t, be2, agg);
    node_fb_kernel<<<(NN + 127) / 128, 256, 0, stream>>>(node_h, agg, Wn1t, bn1,
                                                         Wn2t, bn2, (float*)d_out);
  }
}